// Round 1
// baseline (488.639 us; speedup 1.0000x reference)
//
#include <hip/hip_runtime.h>
#include <hip/hip_bf16.h>
#include <math.h>

// Output layout (floats):
//  image          [128,3,240,256]   off 0          size 23592960
//  names_idxs     [128,960,256]     off 23592960   size 31457280
//  p              [128,256,256]     off 55050240   size 8388608
//  attributes_idxs[128,240,8]       off 63438848   size 245760
//  pal            [128,8,12]        off 63684608   size 12288
#define O_IMG   0
#define O_NAMES 23592960ULL
#define O_P     55050240ULL
#define O_ATTR  63438848ULL
#define O_PAL   63684608ULL

// ---------------- pattern softmax: (b,4,128,128) -> p (b,256,256) ----------
__global__ __launch_bounds__(256) void k_pattern(const float* __restrict__ patterns,
                                                 float* __restrict__ out_p) {
    int idx = blockIdx.x * 256 + threadIdx.x;   // b*16384 + row*128 + col
    int col = idx & 127;
    int row = (idx >> 7) & 127;
    int b   = idx >> 14;
    const float* base = patterns + (size_t)b * 65536 + row * 128 + col;
    float v0 = base[0];
    float v1 = base[16384];
    float v2 = base[2 * 16384];
    float v3 = base[3 * 16384];
    float m = fmaxf(fmaxf(v0, v1), fmaxf(v2, v3));
    float e0 = expf(v0 - m), e1 = expf(v1 - m), e2 = expf(v2 - m), e3 = expf(v3 - m);
    float inv = 1.0f / (e0 + e1 + e2 + e3);
    int ti = row >> 3, pi = row & 7, tj = col >> 3, pj = col & 7;
    size_t o = ((size_t)(b * 256 + ti * 16 + tj) * 64 + pi * 8 + pj) * 4;
    float4 r;
    r.x = e0 * inv; r.y = e1 * inv; r.z = e2 * inv; r.w = e3 * inv;
    *(float4*)(out_p + o) = r;
}

// ---------------- names softmax: one block per (b,t) row of 256 ------------
__global__ __launch_bounds__(256) void k_names(const float* __restrict__ names,
                                               const float* __restrict__ gumbel,
                                               float* __restrict__ out) {
    int t = blockIdx.x % 960;
    int b = blockIdx.x / 960;
    int n = threadIdx.x;
    float v = (names[((size_t)b * 256 + n) * 960 + t] +
               gumbel[((size_t)b * 960 + t) * 256 + n]) * 0.5f;   // /TAU, TAU=2

    __shared__ float redm[4];
    __shared__ float reds[4];
    int lane = threadIdx.x & 63;
    int w    = threadIdx.x >> 6;

    float m = v;
    #pragma unroll
    for (int off = 1; off < 64; off <<= 1) m = fmaxf(m, __shfl_xor(m, off));
    if (lane == 0) redm[w] = m;
    __syncthreads();
    m = fmaxf(fmaxf(redm[0], redm[1]), fmaxf(redm[2], redm[3]));

    float e = expf(v - m);
    float s = e;
    #pragma unroll
    for (int off = 1; off < 64; off <<= 1) s += __shfl_xor(s, off);
    if (lane == 0) reds[w] = s;
    __syncthreads();
    s = reds[0] + reds[1] + reds[2] + reds[3];

    out[((size_t)b * 960 + t) * 256 + n] = e / s;
}

// ---------------- attr softmax (8-wide) + pal copy -------------------------
__global__ __launch_bounds__(256) void k_attr(const float* __restrict__ attributes,
                                              const float* __restrict__ gumbel,
                                              const float* __restrict__ palettes,
                                              float* __restrict__ out_attr,
                                              float* __restrict__ out_pal) {
    int idx = blockIdx.x * 256 + threadIdx.x;   // b*240 + tb
    if (idx < 12288) out_pal[idx] = palettes[idx];
    if (idx >= 128 * 240) return;
    int tb = idx % 240;
    int b  = idx / 240;
    float v[8];
    float m = -1e30f;
    #pragma unroll
    for (int e = 0; e < 8; e++) {
        v[e] = (attributes[((size_t)b * 8 + e) * 240 + tb] +
                gumbel[((size_t)b * 240 + tb) * 8 + e]) * 0.5f;
        m = fmaxf(m, v[e]);
    }
    float s = 0.f;
    #pragma unroll
    for (int e = 0; e < 8; e++) { v[e] = expf(v[e] - m); s += v[e]; }
    float inv = 1.0f / s;
    float* o = out_attr + (size_t)idx * 8;
    #pragma unroll
    for (int e = 0; e < 8; e++) o[e] = v[e] * inv;
}

// ---------------- fused GEMM + colorize + sigmoid + image layout -----------
// block = one (b, nametable row r): tiles t = r*32 .. r*32+31
// monochrome[t, f] = sum_n A[t,n] * P[n,f]   (A = names_idxs, P = p)
// f = px*4+g ; thread owns px = tid&63, 8 tiles (tm=tid>>6, t_local=tm*8+i)
__global__ __launch_bounds__(256) void k_image(const float* __restrict__ A,
                                               const float* __restrict__ P,
                                               const float* __restrict__ attr,
                                               const float* __restrict__ pal,
                                               float* __restrict__ img) {
    int blk = blockIdx.x;
    int r = blk % 30;
    int b = blk / 30;
    int t0 = r * 32;

    __shared__ float sA[32][33];    // [t_local][k]
    __shared__ float sB[32][256];   // [k][f]
    __shared__ float sCol[16][12];  // [tb_local][g*3+c]

    int tid = threadIdx.x;

    // colorization table: tb = (r/2)*16 + tbl, 12 entries each
    if (tid < 192) {
        int tbl = tid / 12;
        int gc  = tid % 12;
        int tb  = (r >> 1) * 16 + tbl;
        const float* at = attr + ((size_t)b * 240 + tb) * 8;
        const float* pl = pal + (size_t)b * 96 + gc;
        float s = 0.f;
        #pragma unroll
        for (int e = 0; e < 8; e++) s += at[e] * pl[e * 12];
        sCol[tbl][gc] = s;
    }

    float acc[8][4];
    #pragma unroll
    for (int i = 0; i < 8; i++)
        #pragma unroll
        for (int j = 0; j < 4; j++) acc[i][j] = 0.f;

    int tf = tid & 63;   // pixel
    int tm = tid >> 6;   // tile-group

    const float* Ab = A + ((size_t)b * 960 + t0) * 256;
    const float* Pb = P + (size_t)b * 65536;

    for (int k0 = 0; k0 < 256; k0 += 32) {
        __syncthreads();
        // A tile 32x32
        #pragma unroll
        for (int i = 0; i < 4; i++) {
            int li = tid + i * 256;
            int tl = li >> 5, kk = li & 31;
            sA[tl][kk] = Ab[(size_t)tl * 256 + k0 + kk];
        }
        // B tile 32x256 (float4)
        #pragma unroll
        for (int i = 0; i < 8; i++) {
            int li = tid + i * 256;          // float4 index
            int kk = li >> 6, ff = (li & 63) * 4;
            *(float4*)&sB[kk][ff] = *(const float4*)&Pb[(size_t)(k0 + kk) * 256 + ff];
        }
        __syncthreads();
        #pragma unroll
        for (int kk = 0; kk < 32; kk++) {
            float4 bv = *(float4*)&sB[kk][tf * 4];
            #pragma unroll
            for (int i = 0; i < 8; i++) {
                float av = sA[tm * 8 + i][kk];
                acc[i][0] += av * bv.x;
                acc[i][1] += av * bv.y;
                acc[i][2] += av * bv.z;
                acc[i][3] += av * bv.w;
            }
        }
    }

    int pi = tf >> 3, pj = tf & 7;
    #pragma unroll
    for (int i = 0; i < 8; i++) {
        int cc  = tm * 8 + i;      // t_local == cc (column in nametable row)
        int tbl = cc >> 1;
        #pragma unroll
        for (int c = 0; c < 3; c++) {
            float s = acc[i][0] * sCol[tbl][c]
                    + acc[i][1] * sCol[tbl][3 + c]
                    + acc[i][2] * sCol[tbl][6 + c]
                    + acc[i][3] * sCol[tbl][9 + c];
            float y = 1.0f / (1.0f + expf(-s));
            img[(((size_t)b * 3 + c) * 240 + r * 8 + pi) * 256 + cc * 8 + pj] = y;
        }
    }
}

extern "C" void kernel_launch(void* const* d_in, const int* in_sizes, int n_in,
                              void* d_out, int out_size, void* d_ws, size_t ws_size,
                              hipStream_t stream) {
    const float* names       = (const float*)d_in[0];
    const float* patterns    = (const float*)d_in[1];
    const float* attributes  = (const float*)d_in[2];
    const float* palettes    = (const float*)d_in[3];
    const float* gumbel_n    = (const float*)d_in[4];
    const float* gumbel_a    = (const float*)d_in[5];
    float* out = (float*)d_out;

    float* out_img   = out + O_IMG;
    float* out_names = out + O_NAMES;
    float* out_p     = out + O_P;
    float* out_attr  = out + O_ATTR;
    float* out_pal   = out + O_PAL;

    // pattern softmax: 128*128*128 threads
    k_pattern<<<8192, 256, 0, stream>>>(patterns, out_p);
    // names softmax: block per (b,t)
    k_names<<<128 * 960, 256, 0, stream>>>(names, gumbel_n, out_names);
    // attr softmax + pal copy
    k_attr<<<120, 256, 0, stream>>>(attributes, gumbel_a, palettes, out_attr, out_pal);
    // fused image
    k_image<<<128 * 30, 256, 0, stream>>>(out_names, out_p, out_attr, palettes, out_img);
}

// Round 2
// 330.223 us; speedup vs baseline: 1.4797x; 1.4797x over previous
//
#include <hip/hip_runtime.h>
#include <hip/hip_bf16.h>
#include <math.h>

// Output layout (floats):
//  image          [128,3,240,256]   off 0          size 23592960
//  names_idxs     [128,960,256]     off 23592960   size 31457280
//  p              [128,256,256]     off 55050240   size 8388608
//  attributes_idxs[128,240,8]       off 63438848   size 245760
//  pal            [128,8,12]        off 63684608   size 12288
#define O_IMG   0
#define O_NAMES 23592960ULL
#define O_P     55050240ULL
#define O_ATTR  63438848ULL
#define O_PAL   63684608ULL

// ---------------- pattern softmax: (b,4,128,128) -> p (b,256,256) ----------
__global__ __launch_bounds__(256) void k_pattern(const float* __restrict__ patterns,
                                                 float* __restrict__ out_p) {
    int idx = blockIdx.x * 256 + threadIdx.x;   // b*16384 + row*128 + col
    int col = idx & 127;
    int row = (idx >> 7) & 127;
    int b   = idx >> 14;
    const float* base = patterns + (size_t)b * 65536 + row * 128 + col;
    float v0 = base[0];
    float v1 = base[16384];
    float v2 = base[2 * 16384];
    float v3 = base[3 * 16384];
    float m = fmaxf(fmaxf(v0, v1), fmaxf(v2, v3));
    float e0 = expf(v0 - m), e1 = expf(v1 - m), e2 = expf(v2 - m), e3 = expf(v3 - m);
    float inv = 1.0f / (e0 + e1 + e2 + e3);
    int ti = row >> 3, pi = row & 7, tj = col >> 3, pj = col & 7;
    size_t o = ((size_t)(b * 256 + ti * 16 + tj) * 64 + pi * 8 + pj) * 4;
    float4 r;
    r.x = e0 * inv; r.y = e1 * inv; r.z = e2 * inv; r.w = e3 * inv;
    *(float4*)(out_p + o) = r;
}

// ---------------- names softmax, t-coalesced ------------------------------
// block = (b, 16 consecutive t). names[b,n,t] read t-contiguously (one 64B
// line per row), staged in LDS [n][17] (stride-17 -> 2-way column aliasing,
// free). One wave per t-row: lane owns 4 n's, shfl-only softmax reduction.
__global__ __launch_bounds__(256) void k_names(const float* __restrict__ names,
                                               const float* __restrict__ gumbel,
                                               float* __restrict__ out) {
    int chunk = blockIdx.x % 60;
    int b     = blockIdx.x / 60;
    int t0 = chunk * 16;
    __shared__ float sN[256 * 17];

    int q = threadIdx.x;
    const float* nb = names + (size_t)b * 245760 + t0;
    {
        int j  = q & 3;       // float4 within the 16-float row slice
        int n0 = q >> 2;      // 64 rows per pass
        #pragma unroll
        for (int pass = 0; pass < 4; pass++) {
            int n = n0 + 64 * pass;
            float4 v = *(const float4*)(nb + (size_t)n * 960 + 4 * j);
            float* dst = sN + n * 17 + 4 * j;
            dst[0] = v.x; dst[1] = v.y; dst[2] = v.z; dst[3] = v.w;
        }
    }
    __syncthreads();

    int lane = q & 63;
    int w    = q >> 6;        // wave 0..3, handles t = w*4 .. w*4+3
    const float* gb = gumbel + ((size_t)b * 960 + t0) * 256;
    float*       ob = out    + ((size_t)b * 960 + t0) * 256;

    #pragma unroll
    for (int tt = 0; tt < 4; tt++) {
        int t = w * 4 + tt;
        float v[4];
        #pragma unroll
        for (int k = 0; k < 4; k++) {
            int n = lane + 64 * k;
            v[k] = (sN[n * 17 + t] + gb[(size_t)t * 256 + n]) * 0.5f;  // /TAU
        }
        float m = fmaxf(fmaxf(v[0], v[1]), fmaxf(v[2], v[3]));
        #pragma unroll
        for (int off = 1; off < 64; off <<= 1) m = fmaxf(m, __shfl_xor(m, off));
        float s = 0.f;
        #pragma unroll
        for (int k = 0; k < 4; k++) { v[k] = expf(v[k] - m); s += v[k]; }
        #pragma unroll
        for (int off = 1; off < 64; off <<= 1) s += __shfl_xor(s, off);
        float inv = 1.0f / s;
        #pragma unroll
        for (int k = 0; k < 4; k++) ob[(size_t)t * 256 + lane + 64 * k] = v[k] * inv;
    }
}

// ---------------- attr softmax (8-wide) + pal copy -------------------------
__global__ __launch_bounds__(256) void k_attr(const float* __restrict__ attributes,
                                              const float* __restrict__ gumbel,
                                              const float* __restrict__ palettes,
                                              float* __restrict__ out_attr,
                                              float* __restrict__ out_pal) {
    int idx = blockIdx.x * 256 + threadIdx.x;   // b*240 + tb
    if (idx < 12288) out_pal[idx] = palettes[idx];
    if (idx >= 128 * 240) return;
    int tb = idx % 240;
    int b  = idx / 240;
    float v[8];
    float m = -1e30f;
    #pragma unroll
    for (int e = 0; e < 8; e++) {
        v[e] = (attributes[((size_t)b * 8 + e) * 240 + tb] +
                gumbel[((size_t)b * 240 + tb) * 8 + e]) * 0.5f;
        m = fmaxf(m, v[e]);
    }
    float s = 0.f;
    #pragma unroll
    for (int e = 0; e < 8; e++) { v[e] = expf(v[e] - m); s += v[e]; }
    float inv = 1.0f / s;
    float* o = out_attr + (size_t)idx * 8;
    #pragma unroll
    for (int e = 0; e < 8; e++) o[e] = v[e] * inv;
}

// ---------------- fused GEMM + colorize + sigmoid + image layout -----------
__global__ __launch_bounds__(256) void k_image(const float* __restrict__ A,
                                               const float* __restrict__ P,
                                               const float* __restrict__ attr,
                                               const float* __restrict__ pal,
                                               float* __restrict__ img) {
    int blk = blockIdx.x;
    int r = blk % 30;
    int b = blk / 30;
    int t0 = r * 32;

    __shared__ float sA[32][33];    // [t_local][k]
    __shared__ float sB[32][256];   // [k][f]
    __shared__ float sCol[16][12];  // [tb_local][g*3+c]

    int tid = threadIdx.x;

    if (tid < 192) {
        int tbl = tid / 12;
        int gc  = tid % 12;
        int tb  = (r >> 1) * 16 + tbl;
        const float* at = attr + ((size_t)b * 240 + tb) * 8;
        const float* pl = pal + (size_t)b * 96 + gc;
        float s = 0.f;
        #pragma unroll
        for (int e = 0; e < 8; e++) s += at[e] * pl[e * 12];
        sCol[tbl][gc] = s;
    }

    float acc[8][4];
    #pragma unroll
    for (int i = 0; i < 8; i++)
        #pragma unroll
        for (int j = 0; j < 4; j++) acc[i][j] = 0.f;

    int tf = tid & 63;   // pixel
    int tm = tid >> 6;   // tile-group

    const float* Ab = A + ((size_t)b * 960 + t0) * 256;
    const float* Pb = P + (size_t)b * 65536;

    for (int k0 = 0; k0 < 256; k0 += 32) {
        __syncthreads();
        #pragma unroll
        for (int i = 0; i < 4; i++) {
            int li = tid + i * 256;
            int tl = li >> 5, kk = li & 31;
            sA[tl][kk] = Ab[(size_t)tl * 256 + k0 + kk];
        }
        #pragma unroll
        for (int i = 0; i < 8; i++) {
            int li = tid + i * 256;          // float4 index
            int kk = li >> 6, ff = (li & 63) * 4;
            *(float4*)&sB[kk][ff] = *(const float4*)&Pb[(size_t)(k0 + kk) * 256 + ff];
        }
        __syncthreads();
        #pragma unroll
        for (int kk = 0; kk < 32; kk++) {
            float4 bv = *(float4*)&sB[kk][tf * 4];
            #pragma unroll
            for (int i = 0; i < 8; i++) {
                float av = sA[tm * 8 + i][kk];
                acc[i][0] += av * bv.x;
                acc[i][1] += av * bv.y;
                acc[i][2] += av * bv.z;
                acc[i][3] += av * bv.w;
            }
        }
    }

    int pi = tf >> 3, pj = tf & 7;
    #pragma unroll
    for (int i = 0; i < 8; i++) {
        int cc  = tm * 8 + i;
        int tbl = cc >> 1;
        #pragma unroll
        for (int c = 0; c < 3; c++) {
            float s = acc[i][0] * sCol[tbl][c]
                    + acc[i][1] * sCol[tbl][3 + c]
                    + acc[i][2] * sCol[tbl][6 + c]
                    + acc[i][3] * sCol[tbl][9 + c];
            float y = 1.0f / (1.0f + expf(-s));
            img[(((size_t)b * 3 + c) * 240 + r * 8 + pi) * 256 + cc * 8 + pj] = y;
        }
    }
}

extern "C" void kernel_launch(void* const* d_in, const int* in_sizes, int n_in,
                              void* d_out, int out_size, void* d_ws, size_t ws_size,
                              hipStream_t stream) {
    const float* names       = (const float*)d_in[0];
    const float* patterns    = (const float*)d_in[1];
    const float* attributes  = (const float*)d_in[2];
    const float* palettes    = (const float*)d_in[3];
    const float* gumbel_n    = (const float*)d_in[4];
    const float* gumbel_a    = (const float*)d_in[5];
    float* out = (float*)d_out;

    float* out_img   = out + O_IMG;
    float* out_names = out + O_NAMES;
    float* out_p     = out + O_P;
    float* out_attr  = out + O_ATTR;
    float* out_pal   = out + O_PAL;

    k_pattern<<<8192, 256, 0, stream>>>(patterns, out_p);
    k_names<<<128 * 60, 256, 0, stream>>>(names, gumbel_n, out_names);
    k_attr<<<120, 256, 0, stream>>>(attributes, gumbel_a, palettes, out_attr, out_pal);
    k_image<<<128 * 30, 256, 0, stream>>>(out_names, out_p, out_attr, palettes, out_img);
}

// Round 3
// 276.044 us; speedup vs baseline: 1.7702x; 1.1963x over previous
//
#include <hip/hip_runtime.h>
#include <hip/hip_bf16.h>
#include <math.h>

// Output layout (floats):
//  image          [128,3,240,256]   off 0
//  names_idxs     [128,960,256]     off 23592960
//  p              [128,256,256]     off 55050240
//  attributes_idxs[128,240,8]       off 63438848
//  pal            [128,8,12]        off 63684608
#define O_IMG   0
#define O_NAMES 23592960ULL
#define O_P     55050240ULL
#define O_ATTR  63438848ULL
#define O_PAL   63684608ULL

typedef __attribute__((ext_vector_type(8))) short short8v;
typedef __attribute__((ext_vector_type(4))) float f32x4;

static __device__ inline unsigned short f2bf(float x) {
    __hip_bfloat16 h = __float2bfloat16(x);
    return *reinterpret_cast<unsigned short*>(&h);
}

// ---------------- pattern softmax (+ optional bf16 P^T to ws) --------------
template<bool WRITE_PT>
__global__ __launch_bounds__(256) void k_pattern_t(const float* __restrict__ patterns,
                                                   float* __restrict__ out_p,
                                                   unsigned short* __restrict__ Pt) {
    int idx = blockIdx.x * 256 + threadIdx.x;   // b*16384 + row*128 + col
    int col = idx & 127;
    int row = (idx >> 7) & 127;
    int b   = idx >> 14;
    const float* base = patterns + (size_t)b * 65536 + row * 128 + col;
    float v0 = base[0];
    float v1 = base[16384];
    float v2 = base[2 * 16384];
    float v3 = base[3 * 16384];
    float m = fmaxf(fmaxf(v0, v1), fmaxf(v2, v3));
    float e0 = expf(v0 - m), e1 = expf(v1 - m), e2 = expf(v2 - m), e3 = expf(v3 - m);
    float inv = 1.0f / (e0 + e1 + e2 + e3);
    float p0 = e0 * inv, p1 = e1 * inv, p2 = e2 * inv, p3 = e3 * inv;
    int ti = row >> 3, pi = row & 7, tj = col >> 3, pj = col & 7;
    int n  = ti * 16 + tj;
    int px = pi * 8 + pj;
    size_t o = ((size_t)(b * 256 + n) * 64 + px) * 4;
    float4 r; r.x = p0; r.y = p1; r.z = p2; r.w = p3;
    *(float4*)(out_p + o) = r;
    if (WRITE_PT) {
        unsigned short* pt = Pt + (size_t)b * 65536 + (size_t)(px * 4) * 256 + n;
        pt[0]   = f2bf(p0);
        pt[256] = f2bf(p1);
        pt[512] = f2bf(p2);
        pt[768] = f2bf(p3);
    }
}

// ---------------- names softmax, t-coalesced (round-2 version) -------------
__global__ __launch_bounds__(256) void k_names(const float* __restrict__ names,
                                               const float* __restrict__ gumbel,
                                               float* __restrict__ out) {
    int chunk = blockIdx.x % 60;
    int b     = blockIdx.x / 60;
    int t0 = chunk * 16;
    __shared__ float sN[256 * 17];

    int q = threadIdx.x;
    const float* nb = names + (size_t)b * 245760 + t0;
    {
        int j  = q & 3;
        int n0 = q >> 2;
        #pragma unroll
        for (int pass = 0; pass < 4; pass++) {
            int n = n0 + 64 * pass;
            float4 v = *(const float4*)(nb + (size_t)n * 960 + 4 * j);
            float* dst = sN + n * 17 + 4 * j;
            dst[0] = v.x; dst[1] = v.y; dst[2] = v.z; dst[3] = v.w;
        }
    }
    __syncthreads();

    int lane = q & 63;
    int w    = q >> 6;
    const float* gb = gumbel + ((size_t)b * 960 + t0) * 256;
    float*       ob = out    + ((size_t)b * 960 + t0) * 256;

    #pragma unroll
    for (int tt = 0; tt < 4; tt++) {
        int t = w * 4 + tt;
        float v[4];
        #pragma unroll
        for (int k = 0; k < 4; k++) {
            int n = lane + 64 * k;
            v[k] = (sN[n * 17 + t] + gb[(size_t)t * 256 + n]) * 0.5f;
        }
        float m = fmaxf(fmaxf(v[0], v[1]), fmaxf(v[2], v[3]));
        #pragma unroll
        for (int off = 1; off < 64; off <<= 1) m = fmaxf(m, __shfl_xor(m, off));
        float s = 0.f;
        #pragma unroll
        for (int k = 0; k < 4; k++) { v[k] = expf(v[k] - m); s += v[k]; }
        #pragma unroll
        for (int off = 1; off < 64; off <<= 1) s += __shfl_xor(s, off);
        float inv = 1.0f / s;
        #pragma unroll
        for (int k = 0; k < 4; k++) ob[(size_t)t * 256 + lane + 64 * k] = v[k] * inv;
    }
}

// ---------------- attr softmax (8-wide) + pal copy -------------------------
__global__ __launch_bounds__(256) void k_attr(const float* __restrict__ attributes,
                                              const float* __restrict__ gumbel,
                                              const float* __restrict__ palettes,
                                              float* __restrict__ out_attr,
                                              float* __restrict__ out_pal) {
    int idx = blockIdx.x * 256 + threadIdx.x;
    if (idx < 12288) out_pal[idx] = palettes[idx];
    if (idx >= 128 * 240) return;
    int tb = idx % 240;
    int b  = idx / 240;
    float v[8];
    float m = -1e30f;
    #pragma unroll
    for (int e = 0; e < 8; e++) {
        v[e] = (attributes[((size_t)b * 8 + e) * 240 + tb] +
                gumbel[((size_t)b * 240 + tb) * 8 + e]) * 0.5f;
        m = fmaxf(m, v[e]);
    }
    float s = 0.f;
    #pragma unroll
    for (int e = 0; e < 8; e++) { v[e] = expf(v[e] - m); s += v[e]; }
    float inv = 1.0f / s;
    float* o = out_attr + (size_t)idx * 8;
    #pragma unroll
    for (int e = 0; e < 8; e++) o[e] = v[e] * inv;
}

// ---------------- MFMA fused GEMM + colorize + sigmoid ---------------------
// block = (b, nametable row r). C[32 t][256 f] = A[32][256k] * P[256k][256f].
// A staged whole (bf16, XOR-swizzled); P^T (ws, bf16 [f][n]) staged per K=32.
__global__ __launch_bounds__(256) void k_image_mfma(const float* __restrict__ A,
                                                    const unsigned short* __restrict__ Pt,
                                                    const float* __restrict__ attr,
                                                    const float* __restrict__ pal,
                                                    float* __restrict__ img) {
    int blk = blockIdx.x;
    int r = blk % 30;
    int b = blk / 30;
    int t0 = r * 32;

    __shared__ __align__(16) char smem[33536];
    char*  sA    = smem;                  // [32][256] bf16, byte ^= (t&7)<<4 per 16B
    char*  sB    = smem + 16384;          // [256][32] bf16, byte ^= (f&7)<<4 per 16B
    float* sMono = (float*)smem;          // [32][256] (union, used after K-loop)
    float* sCol  = (float*)(smem + 32768);// [16][12]

    int tid = threadIdx.x;

    // colorization table
    if (tid < 192) {
        int tbl = tid / 12;
        int gc  = tid % 12;
        int tb  = (r >> 1) * 16 + tbl;
        const float* at = attr + ((size_t)b * 240 + tb) * 8;
        const float* pl = pal + (size_t)b * 96 + gc;
        float s = 0.f;
        #pragma unroll
        for (int e = 0; e < 8; e++) s += at[e] * pl[e * 12];
        sCol[tbl * 12 + gc] = s;
    }

    // stage A (fp32 -> bf16, swizzled): thread = (t = tid>>3, 32-k chunk)
    {
        const float* Ab = A + ((size_t)b * 960 + t0) * 256;
        int t  = tid >> 3;
        int kb = (tid & 7) * 32;
        #pragma unroll
        for (int j = 0; j < 4; j++) {
            int k = kb + j * 8;
            float4 u0 = *(const float4*)(Ab + (size_t)t * 256 + k);
            float4 u1 = *(const float4*)(Ab + (size_t)t * 256 + k + 4);
            short8v h;
            h[0] = f2bf(u0.x); h[1] = f2bf(u0.y); h[2] = f2bf(u0.z); h[3] = f2bf(u0.w);
            h[4] = f2bf(u1.x); h[5] = f2bf(u1.y); h[6] = f2bf(u1.z); h[7] = f2bf(u1.w);
            int off = (t * 512 + k * 2) ^ ((t & 7) << 4);
            *(short8v*)(sA + off) = h;
        }
    }

    f32x4 acc[2][4];
    #pragma unroll
    for (int mi = 0; mi < 2; mi++)
        #pragma unroll
        for (int ni = 0; ni < 4; ni++) acc[mi][ni] = (f32x4){0.f, 0.f, 0.f, 0.f};

    int lane = tid & 63;
    int w    = tid >> 6;
    int lo   = lane & 15;
    int hi   = lane >> 4;

    const unsigned short* Ptb = Pt + (size_t)b * 65536;

    for (int k0 = 0; k0 < 256; k0 += 32) {
        __syncthreads();   // protect sB (and first-pass sA) before overwrite
        {
            int f = tid;
            const unsigned short* src = Ptb + (size_t)f * 256 + k0;
            #pragma unroll
            for (int j = 0; j < 4; j++) {
                short8v v = *(const short8v*)(src + j * 8);
                int off = (f * 64 + j * 16) ^ ((f & 7) << 4);
                *(short8v*)(sB + off) = v;
            }
        }
        __syncthreads();

        int ka = (k0 + hi * 8) * 2;
        short8v a0 = *(short8v*)(sA + ((lo * 512 + ka) ^ ((lo & 7) << 4)));
        short8v a1 = *(short8v*)(sA + (((lo + 16) * 512 + ka) ^ ((lo & 7) << 4)));
        #pragma unroll
        for (int ni = 0; ni < 4; ni++) {
            int f = w * 64 + ni * 16 + lo;
            short8v bf = *(short8v*)(sB + ((f * 64 + hi * 16) ^ ((f & 7) << 4)));
            acc[0][ni] = __builtin_amdgcn_mfma_f32_16x16x32_bf16(a0, bf, acc[0][ni], 0, 0, 0);
            acc[1][ni] = __builtin_amdgcn_mfma_f32_16x16x32_bf16(a1, bf, acc[1][ni], 0, 0, 0);
        }
    }

    __syncthreads();   // K-loop done -> reuse smem as sMono
    #pragma unroll
    for (int mi = 0; mi < 2; mi++)
        #pragma unroll
        for (int ni = 0; ni < 4; ni++) {
            int colf = w * 64 + ni * 16 + lo;
            #pragma unroll
            for (int rg = 0; rg < 4; rg++) {
                int rowt = mi * 16 + hi * 4 + rg;
                sMono[rowt * 256 + colf] = acc[mi][ni][rg];
            }
        }
    __syncthreads();

    int tf = tid & 63;   // pixel
    int tm = tid >> 6;   // tile-group
    int pi = tf >> 3, pj = tf & 7;
    #pragma unroll
    for (int i = 0; i < 8; i++) {
        int cc  = tm * 8 + i;
        int tbl = cc >> 1;
        float4 mv = *(float4*)&sMono[cc * 256 + tf * 4];
        #pragma unroll
        for (int c = 0; c < 3; c++) {
            float s = mv.x * sCol[tbl * 12 + c]
                    + mv.y * sCol[tbl * 12 + 3 + c]
                    + mv.z * sCol[tbl * 12 + 6 + c]
                    + mv.w * sCol[tbl * 12 + 9 + c];
            float y = 1.0f / (1.0f + expf(-s));
            img[(((size_t)b * 3 + c) * 240 + r * 8 + pi) * 256 + cc * 8 + pj] = y;
        }
    }
}

// ---------------- fp32 fallback image kernel (no ws) -----------------------
__global__ __launch_bounds__(256) void k_image_fp32(const float* __restrict__ A,
                                                    const float* __restrict__ P,
                                                    const float* __restrict__ attr,
                                                    const float* __restrict__ pal,
                                                    float* __restrict__ img) {
    int blk = blockIdx.x;
    int r = blk % 30;
    int b = blk / 30;
    int t0 = r * 32;

    __shared__ float sA[32][33];
    __shared__ float sB[32][256];
    __shared__ float sCol[16][12];

    int tid = threadIdx.x;
    if (tid < 192) {
        int tbl = tid / 12;
        int gc  = tid % 12;
        int tb  = (r >> 1) * 16 + tbl;
        const float* at = attr + ((size_t)b * 240 + tb) * 8;
        const float* pl = pal + (size_t)b * 96 + gc;
        float s = 0.f;
        #pragma unroll
        for (int e = 0; e < 8; e++) s += at[e] * pl[e * 12];
        sCol[tbl][gc] = s;
    }

    float acc[8][4];
    #pragma unroll
    for (int i = 0; i < 8; i++)
        #pragma unroll
        for (int j = 0; j < 4; j++) acc[i][j] = 0.f;

    int tf = tid & 63;
    int tm = tid >> 6;

    const float* Ab = A + ((size_t)b * 960 + t0) * 256;
    const float* Pb = P + (size_t)b * 65536;

    for (int k0 = 0; k0 < 256; k0 += 32) {
        __syncthreads();
        #pragma unroll
        for (int i = 0; i < 4; i++) {
            int li = tid + i * 256;
            int tl = li >> 5, kk = li & 31;
            sA[tl][kk] = Ab[(size_t)tl * 256 + k0 + kk];
        }
        #pragma unroll
        for (int i = 0; i < 8; i++) {
            int li = tid + i * 256;
            int kk = li >> 6, ff = (li & 63) * 4;
            *(float4*)&sB[kk][ff] = *(const float4*)&Pb[(size_t)(k0 + kk) * 256 + ff];
        }
        __syncthreads();
        #pragma unroll
        for (int kk = 0; kk < 32; kk++) {
            float4 bv = *(float4*)&sB[kk][tf * 4];
            #pragma unroll
            for (int i = 0; i < 8; i++) {
                float av = sA[tm * 8 + i][kk];
                acc[i][0] += av * bv.x;
                acc[i][1] += av * bv.y;
                acc[i][2] += av * bv.z;
                acc[i][3] += av * bv.w;
            }
        }
    }

    int pi = tf >> 3, pj = tf & 7;
    #pragma unroll
    for (int i = 0; i < 8; i++) {
        int cc  = tm * 8 + i;
        int tbl = cc >> 1;
        #pragma unroll
        for (int c = 0; c < 3; c++) {
            float s = acc[i][0] * sCol[tbl][c]
                    + acc[i][1] * sCol[tbl][3 + c]
                    + acc[i][2] * sCol[tbl][6 + c]
                    + acc[i][3] * sCol[tbl][9 + c];
            float y = 1.0f / (1.0f + expf(-s));
            img[(((size_t)b * 3 + c) * 240 + r * 8 + pi) * 256 + cc * 8 + pj] = y;
        }
    }
}

extern "C" void kernel_launch(void* const* d_in, const int* in_sizes, int n_in,
                              void* d_out, int out_size, void* d_ws, size_t ws_size,
                              hipStream_t stream) {
    const float* names       = (const float*)d_in[0];
    const float* patterns    = (const float*)d_in[1];
    const float* attributes  = (const float*)d_in[2];
    const float* palettes    = (const float*)d_in[3];
    const float* gumbel_n    = (const float*)d_in[4];
    const float* gumbel_a    = (const float*)d_in[5];
    float* out = (float*)d_out;

    float* out_img   = out + O_IMG;
    float* out_names = out + O_NAMES;
    float* out_p     = out + O_P;
    float* out_attr  = out + O_ATTR;
    float* out_pal   = out + O_PAL;

    const size_t PT_BYTES = 128ULL * 256 * 256 * 2;   // 16.78 MB bf16 P^T
    bool use_mfma = (ws_size >= PT_BYTES) && (d_ws != nullptr);

    if (use_mfma) {
        unsigned short* Pt = (unsigned short*)d_ws;
        k_pattern_t<true><<<8192, 256, 0, stream>>>(patterns, out_p, Pt);
        k_names<<<128 * 60, 256, 0, stream>>>(names, gumbel_n, out_names);
        k_attr<<<120, 256, 0, stream>>>(attributes, gumbel_a, palettes, out_attr, out_pal);
        k_image_mfma<<<128 * 30, 256, 0, stream>>>(out_names, Pt, out_attr, palettes, out_img);
    } else {
        k_pattern_t<false><<<8192, 256, 0, stream>>>(patterns, out_p, nullptr);
        k_names<<<128 * 60, 256, 0, stream>>>(names, gumbel_n, out_names);
        k_attr<<<120, 256, 0, stream>>>(attributes, gumbel_a, palettes, out_attr, out_pal);
        k_image_fp32<<<128 * 30, 256, 0, stream>>>(out_names, out_p, out_attr, palettes, out_img);
    }
}

// Round 4
// 222.726 us; speedup vs baseline: 2.1939x; 1.2394x over previous
//
#include <hip/hip_runtime.h>
#include <hip/hip_bf16.h>
#include <math.h>

// Output layout (floats):
//  image          [128,3,240,256]   off 0
//  names_idxs     [128,960,256]     off 23592960
//  p              [128,256,256]     off 55050240
//  attributes_idxs[128,240,8]       off 63438848
//  pal            [128,8,12]        off 63684608
#define O_IMG   0
#define O_NAMES 23592960ULL
#define O_P     55050240ULL
#define O_ATTR  63438848ULL
#define O_PAL   63684608ULL

typedef __attribute__((ext_vector_type(8))) short short8v;
typedef __attribute__((ext_vector_type(4))) float f32x4;

static __device__ inline unsigned short f2bf(float x) {
    __hip_bfloat16 h = __float2bfloat16(x);
    return *reinterpret_cast<unsigned short*>(&h);
}

// ---------------- pattern softmax (+ optional bf16 P^T to ws) --------------
template<bool WRITE_PT>
__global__ __launch_bounds__(256) void k_pattern_t(const float* __restrict__ patterns,
                                                   float* __restrict__ out_p,
                                                   unsigned short* __restrict__ Pt) {
    int idx = blockIdx.x * 256 + threadIdx.x;   // b*16384 + row*128 + col
    int col = idx & 127;
    int row = (idx >> 7) & 127;
    int b   = idx >> 14;
    const float* base = patterns + (size_t)b * 65536 + row * 128 + col;
    float v0 = base[0];
    float v1 = base[16384];
    float v2 = base[2 * 16384];
    float v3 = base[3 * 16384];
    float m = fmaxf(fmaxf(v0, v1), fmaxf(v2, v3));
    float e0 = expf(v0 - m), e1 = expf(v1 - m), e2 = expf(v2 - m), e3 = expf(v3 - m);
    float inv = 1.0f / (e0 + e1 + e2 + e3);
    float p0 = e0 * inv, p1 = e1 * inv, p2 = e2 * inv, p3 = e3 * inv;
    int ti = row >> 3, pi = row & 7, tj = col >> 3, pj = col & 7;
    int n  = ti * 16 + tj;
    int px = pi * 8 + pj;
    size_t o = ((size_t)(b * 256 + n) * 64 + px) * 4;
    float4 r; r.x = p0; r.y = p1; r.z = p2; r.w = p3;
    *(float4*)(out_p + o) = r;
    if (WRITE_PT) {
        unsigned short* pt = Pt + (size_t)b * 65536 + (size_t)(px * 4) * 256 + n;
        pt[0]   = f2bf(p0);
        pt[256] = f2bf(p1);
        pt[512] = f2bf(p2);
        pt[768] = f2bf(p3);
    }
}

// ---------------- names softmax, t-coalesced ------------------------------
__global__ __launch_bounds__(256) void k_names(const float* __restrict__ names,
                                               const float* __restrict__ gumbel,
                                               float* __restrict__ out) {
    int chunk = blockIdx.x % 60;
    int b     = blockIdx.x / 60;
    int t0 = chunk * 16;
    __shared__ float sN[256 * 17];

    int q = threadIdx.x;
    const float* nb = names + (size_t)b * 245760 + t0;
    {
        int j  = q & 3;
        int n0 = q >> 2;
        #pragma unroll
        for (int pass = 0; pass < 4; pass++) {
            int n = n0 + 64 * pass;
            float4 v = *(const float4*)(nb + (size_t)n * 960 + 4 * j);
            float* dst = sN + n * 17 + 4 * j;
            dst[0] = v.x; dst[1] = v.y; dst[2] = v.z; dst[3] = v.w;
        }
    }
    __syncthreads();

    int lane = q & 63;
    int w    = q >> 6;
    const float* gb = gumbel + ((size_t)b * 960 + t0) * 256;
    float*       ob = out    + ((size_t)b * 960 + t0) * 256;

    #pragma unroll
    for (int tt = 0; tt < 4; tt++) {
        int t = w * 4 + tt;
        float v[4];
        #pragma unroll
        for (int k = 0; k < 4; k++) {
            int n = lane + 64 * k;
            v[k] = (sN[n * 17 + t] + gb[(size_t)t * 256 + n]) * 0.5f;
        }
        float m = fmaxf(fmaxf(v[0], v[1]), fmaxf(v[2], v[3]));
        #pragma unroll
        for (int off = 1; off < 64; off <<= 1) m = fmaxf(m, __shfl_xor(m, off));
        float s = 0.f;
        #pragma unroll
        for (int k = 0; k < 4; k++) { v[k] = expf(v[k] - m); s += v[k]; }
        #pragma unroll
        for (int off = 1; off < 64; off <<= 1) s += __shfl_xor(s, off);
        float inv = 1.0f / s;
        #pragma unroll
        for (int k = 0; k < 4; k++) ob[(size_t)t * 256 + lane + 64 * k] = v[k] * inv;
    }
}

// ---------------- attr softmax (8-wide) + pal copy -------------------------
__global__ __launch_bounds__(256) void k_attr(const float* __restrict__ attributes,
                                              const float* __restrict__ gumbel,
                                              const float* __restrict__ palettes,
                                              float* __restrict__ out_attr,
                                              float* __restrict__ out_pal) {
    int idx = blockIdx.x * 256 + threadIdx.x;
    if (idx < 12288) out_pal[idx] = palettes[idx];
    if (idx >= 128 * 240) return;
    int tb = idx % 240;
    int b  = idx / 240;
    float v[8];
    float m = -1e30f;
    #pragma unroll
    for (int e = 0; e < 8; e++) {
        v[e] = (attributes[((size_t)b * 8 + e) * 240 + tb] +
                gumbel[((size_t)b * 240 + tb) * 8 + e]) * 0.5f;
        m = fmaxf(m, v[e]);
    }
    float s = 0.f;
    #pragma unroll
    for (int e = 0; e < 8; e++) { v[e] = expf(v[e] - m); s += v[e]; }
    float inv = 1.0f / s;
    float* o = out_attr + (size_t)idx * 8;
    #pragma unroll
    for (int e = 0; e < 8; e++) o[e] = v[e] * inv;
}

// ---------------- MFMA fused GEMM + colorize + sigmoid ---------------------
// block = (b, nametable row r). C[32 t][256 f] = A[32][256k] * P[256k][256f].
// A staged once in LDS (bf16, XOR-swizzled). B fragments read DIRECTLY from
// global Pt[b][f][n]: lane(lo,hi) loads 16B at Pt[f][k0+hi*8] — the 4 hi
// groups exactly tile each 64B line (coalesced), Pt is L2-hot (30x reuse).
// K-loop has ZERO barriers. Epilogue overlays sMono (16 rows, stride 260)
// on sA, processed in two mi halves.
__global__ __launch_bounds__(256) void k_image_mfma(const float* __restrict__ A,
                                                    const unsigned short* __restrict__ Pt,
                                                    const float* __restrict__ attr,
                                                    const float* __restrict__ pal,
                                                    float* __restrict__ img) {
    int blk = blockIdx.x;
    int r = blk % 30;
    int b = blk / 30;
    int t0 = r * 32;

    __shared__ __align__(16) char smem[16896];   // sA [32][512B] / sMono [16][260]f
    __shared__ float sCol[192];                  // [16][12]

    int tid = threadIdx.x;

    // colorization table
    if (tid < 192) {
        int tbl = tid / 12;
        int gc  = tid % 12;
        int tb  = (r >> 1) * 16 + tbl;
        const float* at = attr + ((size_t)b * 240 + tb) * 8;
        const float* pl = pal + (size_t)b * 96 + gc;
        float s = 0.f;
        #pragma unroll
        for (int e = 0; e < 8; e++) s += at[e] * pl[e * 12];
        sCol[tbl * 12 + gc] = s;
    }

    // stage A (fp32 -> bf16, swizzled): thread = (t = tid>>3, 64B k-chunk)
    {
        const float* Ab = A + ((size_t)b * 960 + t0) * 256;
        int t  = tid >> 3;
        int kb = (tid & 7) * 32;
        #pragma unroll
        for (int j = 0; j < 4; j++) {
            int k = kb + j * 8;
            float4 u0 = *(const float4*)(Ab + (size_t)t * 256 + k);
            float4 u1 = *(const float4*)(Ab + (size_t)t * 256 + k + 4);
            short8v h;
            h[0] = f2bf(u0.x); h[1] = f2bf(u0.y); h[2] = f2bf(u0.z); h[3] = f2bf(u0.w);
            h[4] = f2bf(u1.x); h[5] = f2bf(u1.y); h[6] = f2bf(u1.z); h[7] = f2bf(u1.w);
            int off = (t * 512 + k * 2) ^ ((t & 7) << 4);
            *(short8v*)(smem + off) = h;
        }
    }
    __syncthreads();

    f32x4 acc[2][4];
    #pragma unroll
    for (int mi = 0; mi < 2; mi++)
        #pragma unroll
        for (int ni = 0; ni < 4; ni++) acc[mi][ni] = (f32x4){0.f, 0.f, 0.f, 0.f};

    int lane = tid & 63;
    int w    = tid >> 6;
    int lo   = lane & 15;
    int hi   = lane >> 4;

    const unsigned short* Ptb = Pt + (size_t)b * 65536;

    for (int k0 = 0; k0 < 256; k0 += 32) {
        int ka = (k0 + hi * 8) * 2;
        short8v a0 = *(short8v*)(smem + ((lo * 512 + ka) ^ ((lo & 7) << 4)));
        short8v a1 = *(short8v*)(smem + (((lo + 16) * 512 + ka) ^ ((lo & 7) << 4)));
        #pragma unroll
        for (int ni = 0; ni < 4; ni++) {
            int f = w * 64 + ni * 16 + lo;
            short8v bf = *(const short8v*)(Ptb + (size_t)f * 256 + k0 + hi * 8);
            acc[0][ni] = __builtin_amdgcn_mfma_f32_16x16x32_bf16(a0, bf, acc[0][ni], 0, 0, 0);
            acc[1][ni] = __builtin_amdgcn_mfma_f32_16x16x32_bf16(a1, bf, acc[1][ni], 0, 0, 0);
        }
    }

    // epilogue: two halves of 16 rows through sMono (overlaid on sA)
    float* sMono = (float*)smem;      // [16][260] padded stride
    int tf = tid & 63;
    int tm = tid >> 6;
    int pi = tf >> 3, pj = tf & 7;

    #pragma unroll
    for (int mi = 0; mi < 2; mi++) {
        __syncthreads();   // prior reads of smem/sMono done
        #pragma unroll
        for (int ni = 0; ni < 4; ni++) {
            int colf = w * 64 + ni * 16 + lo;
            #pragma unroll
            for (int rg = 0; rg < 4; rg++)
                sMono[(hi * 4 + rg) * 260 + colf] = acc[mi][ni][rg];
        }
        __syncthreads();
        #pragma unroll
        for (int i = 0; i < 4; i++) {
            int ccl = tm * 4 + i;
            int cc  = mi * 16 + ccl;
            int tbl = cc >> 1;
            float4 mv = *(float4*)&sMono[ccl * 260 + tf * 4];
            #pragma unroll
            for (int c = 0; c < 3; c++) {
                float s = mv.x * sCol[tbl * 12 + c]
                        + mv.y * sCol[tbl * 12 + 3 + c]
                        + mv.z * sCol[tbl * 12 + 6 + c]
                        + mv.w * sCol[tbl * 12 + 9 + c];
                float y = 1.0f / (1.0f + expf(-s));
                img[(((size_t)b * 3 + c) * 240 + r * 8 + pi) * 256 + cc * 8 + pj] = y;
            }
        }
    }
}

// ---------------- fp32 fallback image kernel (no ws) -----------------------
__global__ __launch_bounds__(256) void k_image_fp32(const float* __restrict__ A,
                                                    const float* __restrict__ P,
                                                    const float* __restrict__ attr,
                                                    const float* __restrict__ pal,
                                                    float* __restrict__ img) {
    int blk = blockIdx.x;
    int r = blk % 30;
    int b = blk / 30;
    int t0 = r * 32;

    __shared__ float sA[32][33];
    __shared__ float sB[32][256];
    __shared__ float sColF[16][12];

    int tid = threadIdx.x;
    if (tid < 192) {
        int tbl = tid / 12;
        int gc  = tid % 12;
        int tb  = (r >> 1) * 16 + tbl;
        const float* at = attr + ((size_t)b * 240 + tb) * 8;
        const float* pl = pal + (size_t)b * 96 + gc;
        float s = 0.f;
        #pragma unroll
        for (int e = 0; e < 8; e++) s += at[e] * pl[e * 12];
        sColF[tbl][gc] = s;
    }

    float acc[8][4];
    #pragma unroll
    for (int i = 0; i < 8; i++)
        #pragma unroll
        for (int j = 0; j < 4; j++) acc[i][j] = 0.f;

    int tf = tid & 63;
    int tm = tid >> 6;

    const float* Ab = A + ((size_t)b * 960 + t0) * 256;
    const float* Pb = P + (size_t)b * 65536;

    for (int k0 = 0; k0 < 256; k0 += 32) {
        __syncthreads();
        #pragma unroll
        for (int i = 0; i < 4; i++) {
            int li = tid + i * 256;
            int tl = li >> 5, kk = li & 31;
            sA[tl][kk] = Ab[(size_t)tl * 256 + k0 + kk];
        }
        #pragma unroll
        for (int i = 0; i < 8; i++) {
            int li = tid + i * 256;
            int kk = li >> 6, ff = (li & 63) * 4;
            *(float4*)&sB[kk][ff] = *(const float4*)&Pb[(size_t)(k0 + kk) * 256 + ff];
        }
        __syncthreads();
        #pragma unroll
        for (int kk = 0; kk < 32; kk++) {
            float4 bv = *(float4*)&sB[kk][tf * 4];
            #pragma unroll
            for (int i = 0; i < 8; i++) {
                float av = sA[tm * 8 + i][kk];
                acc[i][0] += av * bv.x;
                acc[i][1] += av * bv.y;
                acc[i][2] += av * bv.z;
                acc[i][3] += av * bv.w;
            }
        }
    }

    int pi = tf >> 3, pj = tf & 7;
    #pragma unroll
    for (int i = 0; i < 8; i++) {
        int cc  = tm * 8 + i;
        int tbl = cc >> 1;
        #pragma unroll
        for (int c = 0; c < 3; c++) {
            float s = acc[i][0] * sColF[tbl][c]
                    + acc[i][1] * sColF[tbl][3 + c]
                    + acc[i][2] * sColF[tbl][6 + c]
                    + acc[i][3] * sColF[tbl][9 + c];
            float y = 1.0f / (1.0f + expf(-s));
            img[(((size_t)b * 3 + c) * 240 + r * 8 + pi) * 256 + cc * 8 + pj] = y;
        }
    }
}

extern "C" void kernel_launch(void* const* d_in, const int* in_sizes, int n_in,
                              void* d_out, int out_size, void* d_ws, size_t ws_size,
                              hipStream_t stream) {
    const float* names       = (const float*)d_in[0];
    const float* patterns    = (const float*)d_in[1];
    const float* attributes  = (const float*)d_in[2];
    const float* palettes    = (const float*)d_in[3];
    const float* gumbel_n    = (const float*)d_in[4];
    const float* gumbel_a    = (const float*)d_in[5];
    float* out = (float*)d_out;

    float* out_img   = out + O_IMG;
    float* out_names = out + O_NAMES;
    float* out_p     = out + O_P;
    float* out_attr  = out + O_ATTR;
    float* out_pal   = out + O_PAL;

    const size_t PT_BYTES = 128ULL * 256 * 256 * 2;   // 16.78 MB bf16 P^T
    bool use_mfma = (ws_size >= PT_BYTES) && (d_ws != nullptr);

    if (use_mfma) {
        unsigned short* Pt = (unsigned short*)d_ws;
        k_pattern_t<true><<<8192, 256, 0, stream>>>(patterns, out_p, Pt);
        k_names<<<128 * 60, 256, 0, stream>>>(names, gumbel_n, out_names);
        k_attr<<<120, 256, 0, stream>>>(attributes, gumbel_a, palettes, out_attr, out_pal);
        k_image_mfma<<<128 * 30, 256, 0, stream>>>(out_names, Pt, out_attr, palettes, out_img);
    } else {
        k_pattern_t<false><<<8192, 256, 0, stream>>>(patterns, out_p, nullptr);
        k_names<<<128 * 60, 256, 0, stream>>>(names, gumbel_n, out_names);
        k_attr<<<120, 256, 0, stream>>>(attributes, gumbel_a, palettes, out_attr, out_pal);
        k_image_fp32<<<128 * 30, 256, 0, stream>>>(out_names, out_p, out_attr, palettes, out_img);
    }
}

// Round 5
// 185.846 us; speedup vs baseline: 2.6293x; 1.1984x over previous
//
#include <hip/hip_runtime.h>
#include <hip/hip_bf16.h>
#include <math.h>

// Output layout (floats):
//  image          [128,3,240,256]   off 0
//  names_idxs     [128,960,256]     off 23592960
//  p              [128,256,256]     off 55050240
//  attributes_idxs[128,240,8]       off 63438848
//  pal            [128,8,12]        off 63684608
#define O_IMG   0
#define O_NAMES 23592960ULL
#define O_P     55050240ULL
#define O_ATTR  63438848ULL
#define O_PAL   63684608ULL

typedef __attribute__((ext_vector_type(8))) short short8v;
typedef __attribute__((ext_vector_type(4))) float f32x4;

static __device__ inline unsigned short f2bf(float x) {
    __hip_bfloat16 h = __float2bfloat16(x);
    return *reinterpret_cast<unsigned short*>(&h);
}

// ---------------- pattern softmax (+ optional bf16 P^T to ws) --------------
template<bool WRITE_PT>
__global__ __launch_bounds__(256) void k_pattern_t(const float* __restrict__ patterns,
                                                   float* __restrict__ out_p,
                                                   unsigned short* __restrict__ Pt) {
    int idx = blockIdx.x * 256 + threadIdx.x;   // b*16384 + row*128 + col
    int col = idx & 127;
    int row = (idx >> 7) & 127;
    int b   = idx >> 14;
    const float* base = patterns + (size_t)b * 65536 + row * 128 + col;
    float v0 = base[0];
    float v1 = base[16384];
    float v2 = base[2 * 16384];
    float v3 = base[3 * 16384];
    float m = fmaxf(fmaxf(v0, v1), fmaxf(v2, v3));
    float e0 = expf(v0 - m), e1 = expf(v1 - m), e2 = expf(v2 - m), e3 = expf(v3 - m);
    float inv = 1.0f / (e0 + e1 + e2 + e3);
    float p0 = e0 * inv, p1 = e1 * inv, p2 = e2 * inv, p3 = e3 * inv;
    int ti = row >> 3, pi = row & 7, tj = col >> 3, pj = col & 7;
    int n  = ti * 16 + tj;
    int px = pi * 8 + pj;
    size_t o = ((size_t)(b * 256 + n) * 64 + px) * 4;
    float4 r; r.x = p0; r.y = p1; r.z = p2; r.w = p3;
    *(float4*)(out_p + o) = r;
    if (WRITE_PT) {
        unsigned short* pt = Pt + (size_t)b * 65536 + (size_t)(px * 4) * 256 + n;
        pt[0]   = f2bf(p0);
        pt[256] = f2bf(p1);
        pt[512] = f2bf(p2);
        pt[768] = f2bf(p3);
    }
}

// ---------------- names softmax, t-coalesced ------------------------------
__global__ __launch_bounds__(256) void k_names(const float* __restrict__ names,
                                               const float* __restrict__ gumbel,
                                               float* __restrict__ out) {
    int chunk = blockIdx.x % 60;
    int b     = blockIdx.x / 60;
    int t0 = chunk * 16;
    __shared__ float sN[256 * 17];

    int q = threadIdx.x;
    const float* nb = names + (size_t)b * 245760 + t0;
    {
        int j  = q & 3;
        int n0 = q >> 2;
        #pragma unroll
        for (int pass = 0; pass < 4; pass++) {
            int n = n0 + 64 * pass;
            float4 v = *(const float4*)(nb + (size_t)n * 960 + 4 * j);
            float* dst = sN + n * 17 + 4 * j;
            dst[0] = v.x; dst[1] = v.y; dst[2] = v.z; dst[3] = v.w;
        }
    }
    __syncthreads();

    int lane = q & 63;
    int w    = q >> 6;
    const float* gb = gumbel + ((size_t)b * 960 + t0) * 256;
    float*       ob = out    + ((size_t)b * 960 + t0) * 256;

    #pragma unroll
    for (int tt = 0; tt < 4; tt++) {
        int t = w * 4 + tt;
        float v[4];
        #pragma unroll
        for (int k = 0; k < 4; k++) {
            int n = lane + 64 * k;
            v[k] = (sN[n * 17 + t] + gb[(size_t)t * 256 + n]) * 0.5f;
        }
        float m = fmaxf(fmaxf(v[0], v[1]), fmaxf(v[2], v[3]));
        #pragma unroll
        for (int off = 1; off < 64; off <<= 1) m = fmaxf(m, __shfl_xor(m, off));
        float s = 0.f;
        #pragma unroll
        for (int k = 0; k < 4; k++) { v[k] = expf(v[k] - m); s += v[k]; }
        #pragma unroll
        for (int off = 1; off < 64; off <<= 1) s += __shfl_xor(s, off);
        float inv = 1.0f / s;
        #pragma unroll
        for (int k = 0; k < 4; k++) ob[(size_t)t * 256 + lane + 64 * k] = v[k] * inv;
    }
}

// ---------------- attr softmax (8-wide) + pal copy -------------------------
__global__ __launch_bounds__(256) void k_attr(const float* __restrict__ attributes,
                                              const float* __restrict__ gumbel,
                                              const float* __restrict__ palettes,
                                              float* __restrict__ out_attr,
                                              float* __restrict__ out_pal) {
    int idx = blockIdx.x * 256 + threadIdx.x;
    if (idx < 12288) out_pal[idx] = palettes[idx];
    if (idx >= 128 * 240) return;
    int tb = idx % 240;
    int b  = idx / 240;
    float v[8];
    float m = -1e30f;
    #pragma unroll
    for (int e = 0; e < 8; e++) {
        v[e] = (attributes[((size_t)b * 8 + e) * 240 + tb] +
                gumbel[((size_t)b * 240 + tb) * 8 + e]) * 0.5f;
        m = fmaxf(m, v[e]);
    }
    float s = 0.f;
    #pragma unroll
    for (int e = 0; e < 8; e++) { v[e] = expf(v[e] - m); s += v[e]; }
    float inv = 1.0f / s;
    float* o = out_attr + (size_t)idx * 8;
    #pragma unroll
    for (int e = 0; e < 8; e++) o[e] = v[e] * inv;
}

// ---------------- MFMA fused GEMM + colorize + sigmoid, BM=64 --------------
// block = (b, rr): 64 tile-rows t0=rr*64 (nametable rows 2rr, 2rr+1).
// Grid decoded so all 15 blocks of a batch land on ONE XCD (Pt slice L2-hot).
// A staged once (bf16, swizzled). B frags direct from global Pt[b][f][n],
// double-buffered in registers (bcur/bnxt) one k-step ahead. Zero K barriers.
__global__ __launch_bounds__(256) void k_image_mfma(const float* __restrict__ A,
                                                    const unsigned short* __restrict__ Pt,
                                                    const float* __restrict__ attr,
                                                    const float* __restrict__ pal,
                                                    float* __restrict__ img) {
    // XCD-aware decode: j%8 = XCD; batches b with b%8==x stay on XCD x.
    int j  = blockIdx.x;
    int x  = j & 7;
    int s  = j >> 3;          // 0..239
    int q  = s / 15;
    int rr = s % 15;          // 0..14
    int b  = x + 8 * q;       // 0..127
    int t0 = rr * 64;

    __shared__ __align__(16) char smem[32768];   // sA [64][512B] / sMono [16][260]f
    __shared__ float sCol[192];                  // [16][12]

    int tid = threadIdx.x;

    // colorization table (both nametable rows share tb row rr)
    if (tid < 192) {
        int tbl = tid / 12;
        int gc  = tid % 12;
        int tb  = rr * 16 + tbl;
        const float* at = attr + ((size_t)b * 240 + tb) * 8;
        const float* pl = pal + (size_t)b * 96 + gc;
        float sum = 0.f;
        #pragma unroll
        for (int e = 0; e < 8; e++) sum += at[e] * pl[e * 12];
        sCol[tbl * 12 + gc] = sum;
    }

    // stage A (fp32 -> bf16, swizzled): thread = (t = tid>>2, 64-k chunk)
    {
        const float* Ab = A + ((size_t)b * 960 + t0) * 256;
        int t  = tid >> 2;
        int kb = (tid & 3) * 64;
        #pragma unroll
        for (int jj = 0; jj < 8; jj++) {
            int k = kb + jj * 8;
            float4 u0 = *(const float4*)(Ab + (size_t)t * 256 + k);
            float4 u1 = *(const float4*)(Ab + (size_t)t * 256 + k + 4);
            short8v h;
            h[0] = f2bf(u0.x); h[1] = f2bf(u0.y); h[2] = f2bf(u0.z); h[3] = f2bf(u0.w);
            h[4] = f2bf(u1.x); h[5] = f2bf(u1.y); h[6] = f2bf(u1.z); h[7] = f2bf(u1.w);
            int off = (t * 512 + k * 2) ^ ((t & 7) << 4);
            *(short8v*)(smem + off) = h;
        }
    }
    __syncthreads();

    f32x4 acc[4][4];
    #pragma unroll
    for (int mi = 0; mi < 4; mi++)
        #pragma unroll
        for (int ni = 0; ni < 4; ni++) acc[mi][ni] = (f32x4){0.f, 0.f, 0.f, 0.f};

    int lane = tid & 63;
    int w    = tid >> 6;
    int lo   = lane & 15;
    int hi   = lane >> 4;

    const unsigned short* Ptb = Pt + (size_t)b * 65536 + hi * 8;

    // register-double-buffered B fragments
    short8v bcur[4], bnxt[4];
    #pragma unroll
    for (int ni = 0; ni < 4; ni++) {
        int f = w * 64 + ni * 16 + lo;
        bcur[ni] = *(const short8v*)(Ptb + (size_t)f * 256);
    }

    #pragma unroll
    for (int k0 = 0; k0 < 256; k0 += 32) {
        if (k0 < 224) {
            #pragma unroll
            for (int ni = 0; ni < 4; ni++) {
                int f = w * 64 + ni * 16 + lo;
                bnxt[ni] = *(const short8v*)(Ptb + (size_t)f * 256 + k0 + 32);
            }
        }
        int ka = (k0 + hi * 8) * 2;
        short8v a0 = *(short8v*)(smem + (((lo      ) * 512 + ka) ^ ((lo & 7) << 4)));
        short8v a1 = *(short8v*)(smem + (((lo + 16) * 512 + ka) ^ ((lo & 7) << 4)));
        short8v a2 = *(short8v*)(smem + (((lo + 32) * 512 + ka) ^ ((lo & 7) << 4)));
        short8v a3 = *(short8v*)(smem + (((lo + 48) * 512 + ka) ^ ((lo & 7) << 4)));
        #pragma unroll
        for (int ni = 0; ni < 4; ni++) {
            acc[0][ni] = __builtin_amdgcn_mfma_f32_16x16x32_bf16(a0, bcur[ni], acc[0][ni], 0, 0, 0);
            acc[1][ni] = __builtin_amdgcn_mfma_f32_16x16x32_bf16(a1, bcur[ni], acc[1][ni], 0, 0, 0);
            acc[2][ni] = __builtin_amdgcn_mfma_f32_16x16x32_bf16(a2, bcur[ni], acc[2][ni], 0, 0, 0);
            acc[3][ni] = __builtin_amdgcn_mfma_f32_16x16x32_bf16(a3, bcur[ni], acc[3][ni], 0, 0, 0);
        }
        if (k0 < 224) {
            #pragma unroll
            for (int ni = 0; ni < 4; ni++) bcur[ni] = bnxt[ni];
        }
    }

    // epilogue: 4 phases of 16 rows through sMono (overlaid on sA)
    float* sMono = (float*)smem;      // [16][260] padded stride
    int tf = tid & 63;
    int tm = tid >> 6;
    int pi = tf >> 3, pj = tf & 7;

    #pragma unroll
    for (int mi = 0; mi < 4; mi++) {
        __syncthreads();   // prior reads of smem done
        #pragma unroll
        for (int ni = 0; ni < 4; ni++) {
            int colf = w * 64 + ni * 16 + lo;
            #pragma unroll
            for (int rg = 0; rg < 4; rg++)
                sMono[(hi * 4 + rg) * 260 + colf] = acc[mi][ni][rg];
        }
        __syncthreads();
        int r    = rr * 2 + (mi >> 1);      // nametable row
        int cbase = (mi & 1) * 16;          // column base within the row
        #pragma unroll
        for (int i = 0; i < 4; i++) {
            int ccl  = tm * 4 + i;          // 0..15
            int ccol = cbase + ccl;         // 0..31
            int tbl  = ccol >> 1;
            float4 mv = *(float4*)&sMono[ccl * 260 + tf * 4];
            #pragma unroll
            for (int c = 0; c < 3; c++) {
                float sv = mv.x * sCol[tbl * 12 + c]
                         + mv.y * sCol[tbl * 12 + 3 + c]
                         + mv.z * sCol[tbl * 12 + 6 + c]
                         + mv.w * sCol[tbl * 12 + 9 + c];
                float y = 1.0f / (1.0f + expf(-sv));
                img[(((size_t)b * 3 + c) * 240 + r * 8 + pi) * 256 + ccol * 8 + pj] = y;
            }
        }
    }
}

// ---------------- fp32 fallback image kernel (no ws) -----------------------
__global__ __launch_bounds__(256) void k_image_fp32(const float* __restrict__ A,
                                                    const float* __restrict__ P,
                                                    const float* __restrict__ attr,
                                                    const float* __restrict__ pal,
                                                    float* __restrict__ img) {
    int blk = blockIdx.x;
    int r = blk % 30;
    int b = blk / 30;
    int t0 = r * 32;

    __shared__ float sA[32][33];
    __shared__ float sB[32][256];
    __shared__ float sColF[16][12];

    int tid = threadIdx.x;
    if (tid < 192) {
        int tbl = tid / 12;
        int gc  = tid % 12;
        int tb  = (r >> 1) * 16 + tbl;
        const float* at = attr + ((size_t)b * 240 + tb) * 8;
        const float* pl = pal + (size_t)b * 96 + gc;
        float s = 0.f;
        #pragma unroll
        for (int e = 0; e < 8; e++) s += at[e] * pl[e * 12];
        sColF[tbl][gc] = s;
    }

    float acc[8][4];
    #pragma unroll
    for (int i = 0; i < 8; i++)
        #pragma unroll
        for (int j = 0; j < 4; j++) acc[i][j] = 0.f;

    int tf = tid & 63;
    int tm = tid >> 6;

    const float* Ab = A + ((size_t)b * 960 + t0) * 256;
    const float* Pb = P + (size_t)b * 65536;

    for (int k0 = 0; k0 < 256; k0 += 32) {
        __syncthreads();
        #pragma unroll
        for (int i = 0; i < 4; i++) {
            int li = tid + i * 256;
            int tl = li >> 5, kk = li & 31;
            sA[tl][kk] = Ab[(size_t)tl * 256 + k0 + kk];
        }
        #pragma unroll
        for (int i = 0; i < 8; i++) {
            int li = tid + i * 256;
            int kk = li >> 6, ff = (li & 63) * 4;
            *(float4*)&sB[kk][ff] = *(const float4*)&Pb[(size_t)(k0 + kk) * 256 + ff];
        }
        __syncthreads();
        #pragma unroll
        for (int kk = 0; kk < 32; kk++) {
            float4 bv = *(float4*)&sB[kk][tf * 4];
            #pragma unroll
            for (int i = 0; i < 8; i++) {
                float av = sA[tm * 8 + i][kk];
                acc[i][0] += av * bv.x;
                acc[i][1] += av * bv.y;
                acc[i][2] += av * bv.z;
                acc[i][3] += av * bv.w;
            }
        }
    }

    int pi = tf >> 3, pj = tf & 7;
    #pragma unroll
    for (int i = 0; i < 8; i++) {
        int cc  = tm * 8 + i;
        int tbl = cc >> 1;
        #pragma unroll
        for (int c = 0; c < 3; c++) {
            float s = acc[i][0] * sColF[tbl][c]
                    + acc[i][1] * sColF[tbl][3 + c]
                    + acc[i][2] * sColF[tbl][6 + c]
                    + acc[i][3] * sColF[tbl][9 + c];
            float y = 1.0f / (1.0f + expf(-s));
            img[(((size_t)b * 3 + c) * 240 + r * 8 + pi) * 256 + cc * 8 + pj] = y;
        }
    }
}

extern "C" void kernel_launch(void* const* d_in, const int* in_sizes, int n_in,
                              void* d_out, int out_size, void* d_ws, size_t ws_size,
                              hipStream_t stream) {
    const float* names       = (const float*)d_in[0];
    const float* patterns    = (const float*)d_in[1];
    const float* attributes  = (const float*)d_in[2];
    const float* palettes    = (const float*)d_in[3];
    const float* gumbel_n    = (const float*)d_in[4];
    const float* gumbel_a    = (const float*)d_in[5];
    float* out = (float*)d_out;

    float* out_img   = out + O_IMG;
    float* out_names = out + O_NAMES;
    float* out_p     = out + O_P;
    float* out_attr  = out + O_ATTR;
    float* out_pal   = out + O_PAL;

    const size_t PT_BYTES = 128ULL * 256 * 256 * 2;   // 16.78 MB bf16 P^T
    bool use_mfma = (ws_size >= PT_BYTES) && (d_ws != nullptr);

    if (use_mfma) {
        unsigned short* Pt = (unsigned short*)d_ws;
        k_pattern_t<true><<<8192, 256, 0, stream>>>(patterns, out_p, Pt);
        k_names<<<128 * 60, 256, 0, stream>>>(names, gumbel_n, out_names);
        k_attr<<<120, 256, 0, stream>>>(attributes, gumbel_a, palettes, out_attr, out_pal);
        k_image_mfma<<<1920, 256, 0, stream>>>(out_names, Pt, out_attr, palettes, out_img);
    } else {
        k_pattern_t<false><<<8192, 256, 0, stream>>>(patterns, out_p, nullptr);
        k_names<<<128 * 60, 256, 0, stream>>>(names, gumbel_n, out_names);
        k_attr<<<120, 256, 0, stream>>>(attributes, gumbel_a, palettes, out_attr, out_pal);
        k_image_fp32<<<128 * 30, 256, 0, stream>>>(out_names, out_p, out_attr, palettes, out_img);
    }
}